// Round 1
// baseline (413.319 us; speedup 1.0000x reference)
//
#include <hip/hip_runtime.h>
#include <hip/hip_bf16.h>

#define TT 2048
#define DM 2048
#define NH 16
#define KVH 4
#define HD 128

typedef __attribute__((ext_vector_type(8))) short bs8;
typedef __attribute__((ext_vector_type(4))) float fx4;
typedef __attribute__((ext_vector_type(4))) unsigned short us4;

__device__ inline unsigned short f2b(float f) {
  __hip_bfloat16 h = __float2bfloat16(f);
  return *reinterpret_cast<unsigned short*>(&h);
}

__device__ inline void gld_lds16(const ushort* g, ushort* l) {
  __builtin_amdgcn_global_load_lds(
      (const __attribute__((address_space(1))) void*)g,
      (__attribute__((address_space(3))) void*)l,
      16, 0, 0);
}

// ---------------- cast x: fp32 -> bf16, 4 elems/thread ----------------
__global__ __launch_bounds__(256) void cast_f32_bf16(const float* __restrict__ in,
                                                     ushort* __restrict__ out) {
  int i = blockIdx.x * 256 + threadIdx.x;
  float4 v = ((const float4*)in)[i];
  us4 o = {f2b(v.x), f2b(v.y), f2b(v.z), f2b(v.w)};
  ((us4*)out)[i] = o;
}

// ---------------- transpose+cast weight: W[K][N] fp32 -> Wt[N][K] bf16 ----------------
__global__ __launch_bounds__(256) void transpose_cast(const float* __restrict__ W,
                                                      ushort* __restrict__ Wt,
                                                      int K, int N) {
  __shared__ float t[32][33];
  int tx = threadIdx.x, ty = threadIdx.y;        // block (32,8)
  int n0 = blockIdx.x * 32, k0 = blockIdx.y * 32;
  for (int jj = 0; jj < 4; ++jj)
    t[ty + jj * 8][tx] = W[(size_t)(k0 + ty + jj * 8) * N + n0 + tx];
  __syncthreads();
  for (int jj = 0; jj < 4; ++jj)
    Wt[(size_t)(n0 + ty + jj * 8) * K + k0 + tx] = f2b(t[tx][ty + jj * 8]);
}

// ---------------- GEMM: C = A[M][K] * Bt[N][K]^T  (bf16 in, fp32 acc) ----------------
// MODE 0: bf16 row-major [M][N]
// MODE 1: bf16 k-layout  [b][g][t][d]
// MODE 2: bf16 v-layout  [b][g][d][t]  (transposed for attention PV)
// MODE 3: fp32 row-major [M][N]
template <int MODE>
__global__ __launch_bounds__(256) void gemm_bt(const ushort* __restrict__ A,
                                               const ushort* __restrict__ Bt,
                                               void* __restrict__ Cout,
                                               int M, int N, int K) {
  __shared__ alignas(16) ushort As[128 * 64];
  __shared__ alignas(16) ushort Bs[128 * 64];
  const int tid = threadIdx.x;
  const int lane = tid & 63;
  const int wid = tid >> 6;
  const int wm = wid >> 1, wn = wid & 1;
  const int quad = lane >> 4, l16 = lane & 15;
  const int bm = blockIdx.y * 128, bn = blockIdx.x * 128;

  fx4 acc[4][4];
  for (int i = 0; i < 4; ++i)
    for (int j = 0; j < 4; ++j) acc[i][j] = (fx4){0.f, 0.f, 0.f, 0.f};

  const int r8 = lane >> 3, s8 = lane & 7;
  for (int k0 = 0; k0 < K; k0 += 64) {
    // stage A and Bt tiles (128x64 each), XOR-swizzled chunks, 16B per lane
    for (int i = 0; i < 4; ++i) {
      int m = i * 32 + wid * 8 + r8;
      int c = s8 ^ (m & 7);
      gld_lds16(A + (size_t)(bm + m) * K + k0 + c * 8, As + (i * 32 + wid * 8) * 64);
      gld_lds16(Bt + (size_t)(bn + m) * K + k0 + c * 8, Bs + (i * 32 + wid * 8) * 64);
    }
    __syncthreads();
    for (int ks = 0; ks < 2; ++ks) {
      bs8 af[4], bf[4];
      for (int mt = 0; mt < 4; ++mt) {
        int m = wm * 64 + mt * 16 + l16;
        int c = ks * 4 + quad;
        int slot = c ^ (m & 7);
        af[mt] = *(const bs8*)(As + m * 64 + slot * 8);
      }
      for (int nt = 0; nt < 4; ++nt) {
        int n = wn * 64 + nt * 16 + l16;
        int c = ks * 4 + quad;
        int slot = c ^ (n & 7);
        bf[nt] = *(const bs8*)(Bs + n * 64 + slot * 8);
      }
      for (int mt = 0; mt < 4; ++mt)
        for (int nt = 0; nt < 4; ++nt)
          acc[mt][nt] = __builtin_amdgcn_mfma_f32_16x16x32_bf16(af[mt], bf[nt],
                                                                acc[mt][nt], 0, 0, 0);
    }
    __syncthreads();
  }

  for (int mt = 0; mt < 4; ++mt)
    for (int nt = 0; nt < 4; ++nt)
      for (int r = 0; r < 4; ++r) {
        int row = bm + wm * 64 + mt * 16 + quad * 4 + r;
        int col = bn + wn * 64 + nt * 16 + l16;
        float v = acc[mt][nt][r];
        if (MODE == 0) {
          ((ushort*)Cout)[(size_t)row * N + col] = f2b(v);
        } else if (MODE == 1) {
          int b = row >> 11, t = row & 2047;
          int gg = col >> 7, d = col & 127;
          ((ushort*)Cout)[((size_t)(b * KVH + gg) * TT + t) * HD + d] = f2b(v);
        } else if (MODE == 2) {
          int b = row >> 11, t = row & 2047;
          int gg = col >> 7, d = col & 127;
          ((ushort*)Cout)[((size_t)(b * KVH + gg) * HD + d) * TT + t] = f2b(v);
        } else {
          ((float*)Cout)[(size_t)row * N + col] = v;
        }
      }
}

// ---------------- fused causal WGQA attention (flash-style, S^T form) ----------------
// grid = B * NH * (TT/128); block = 256 (4 waves); wave owns 32 queries.
__global__ __launch_bounds__(256) void attn_kernel(const ushort* __restrict__ qb,
                                                   const ushort* __restrict__ kb,
                                                   const ushort* __restrict__ vt,
                                                   ushort* __restrict__ yb,
                                                   const float* __restrict__ wlog) {
  __shared__ alignas(16) ushort Ks[64 * 128];   // [key][d], chunk-swizzled
  __shared__ alignas(16) ushort Vs[128 * 64];   // [d][key], chunk-swizzled
  __shared__ alignas(16) ushort Ps[128 * 72];   // [q][key], stride 72 (pad)

  const int bid = blockIdx.x;
  const int qt = bid & 15;
  const int h = (bid >> 4) & 15;
  const int b = bid >> 8;
  const int g = h >> 2;
  const int tid = threadIdx.x;
  const int lane = tid & 63;
  const int wid = tid >> 6;
  const int quad = lane >> 4;
  const int l16 = lane & 15;
  const int q0 = qt * 128;
  const int qw = q0 + wid * 32;

  const float scale = wlog[g] * 0.08838834764831845f;  // 1/sqrt(128)

  // Q fragments in registers for the whole block (B-operand of S^T = K * Q^T)
  bs8 qf[2][4];
  for (int nt = 0; nt < 2; ++nt) {
    int q = qw + nt * 16 + l16;
    const ushort* qrow = qb + ((size_t)(b * TT + q) * NH + h) * HD;
    for (int ks = 0; ks < 4; ++ks)
      qf[nt][ks] = *(const bs8*)(qrow + ks * 32 + quad * 8);
  }

  float m_i[2] = {-INFINITY, -INFINITY};
  float l_i[2] = {0.f, 0.f};
  fx4 o[8][2];
  for (int i = 0; i < 8; ++i)
    for (int nt = 0; nt < 2; ++nt) o[i][nt] = (fx4){0.f, 0.f, 0.f, 0.f};

  const ushort* kbase = kb + (size_t)(b * KVH + g) * TT * HD;
  const ushort* vbase = vt + (size_t)(b * KVH + g) * HD * TT;
  const int jmax = 2 * qt + 1;

  for (int j = 0; j <= jmax; ++j) {
    // ---- stage K tile (64 keys x 128 d) and V^T tile (128 d x 64 keys) ----
    {
      int r4 = lane >> 4, s = lane & 15;
      for (int i = 0; i < 4; ++i) {
        int key = i * 16 + wid * 4 + r4;
        int c = (s & 8) | ((s ^ key) & 7);
        gld_lds16(kbase + (size_t)(j * 64 + key) * HD + c * 8,
                  Ks + (i * 16 + wid * 4) * 128);
      }
      int r8 = lane >> 3, s8 = lane & 7;
      for (int i = 0; i < 4; ++i) {
        int d = i * 32 + wid * 8 + r8;
        int c = s8 ^ (d & 7);
        gld_lds16(vbase + (size_t)d * TT + j * 64 + c * 8,
                  Vs + (i * 32 + wid * 8) * 64);
      }
    }
    __syncthreads();

    if (j * 64 <= qw + 31) {  // wave has at least one unmasked key
      // ---- S^T = K * Q^T  (keys x queries), fp32 acc ----
      fx4 s[2][4];
      for (int nt = 0; nt < 2; ++nt)
        for (int mt = 0; mt < 4; ++mt) s[nt][mt] = (fx4){0.f, 0.f, 0.f, 0.f};
      for (int mt = 0; mt < 4; ++mt) {
        bs8 a[4];
        int key = mt * 16 + l16;
        for (int ks = 0; ks < 4; ++ks) {
          int c = ks * 4 + quad;
          int slot = (c & 8) | ((c ^ key) & 7);
          a[ks] = *(const bs8*)(Ks + key * 128 + slot * 8);
        }
        for (int nt = 0; nt < 2; ++nt)
          for (int ks = 0; ks < 4; ++ks)
            s[nt][mt] = __builtin_amdgcn_mfma_f32_16x16x32_bf16(a[ks], qf[nt][ks],
                                                                s[nt][mt], 0, 0, 0);
      }

      // ---- scale + causal mask ----
      const bool diag = (j >= 2 * qt);
      for (int nt = 0; nt < 2; ++nt) {
        int q = qw + nt * 16 + l16;
        for (int mt = 0; mt < 4; ++mt)
          for (int r = 0; r < 4; ++r) {
            float v = s[nt][mt][r] * scale;
            if (diag) {
              int key = j * 64 + mt * 16 + quad * 4 + r;
              if (key > q) v = -1e30f;
            }
            s[nt][mt][r] = v;
          }
      }

      // ---- online softmax (stats per query = per column, mostly in-lane) ----
      for (int nt = 0; nt < 2; ++nt) {
        float mx = s[nt][0][0];
        for (int mt = 0; mt < 4; ++mt)
          for (int r = 0; r < 4; ++r) mx = fmaxf(mx, s[nt][mt][r]);
        mx = fmaxf(mx, __shfl_xor(mx, 16));
        mx = fmaxf(mx, __shfl_xor(mx, 32));
        float m_new = fmaxf(m_i[nt], mx);
        float alpha = __expf(m_i[nt] - m_new);
        float sum = 0.f;
        for (int mt = 0; mt < 4; ++mt)
          for (int r = 0; r < 4; ++r) {
            float p = __expf(s[nt][mt][r] - m_new);
            s[nt][mt][r] = p;
            sum += p;
          }
        sum += __shfl_xor(sum, 16);
        sum += __shfl_xor(sum, 32);
        l_i[nt] = l_i[nt] * alpha + sum;
        m_i[nt] = m_new;
        for (int dmt = 0; dmt < 8; ++dmt)
          for (int r = 0; r < 4; ++r) o[dmt][nt][r] *= alpha;
        // write P (bf16) to LDS in [q][key] layout for the PV B-operand
        int qrow = wid * 32 + nt * 16 + l16;
        for (int mt = 0; mt < 4; ++mt) {
          us4 pw = {f2b(s[nt][mt][0]), f2b(s[nt][mt][1]),
                    f2b(s[nt][mt][2]), f2b(s[nt][mt][3])};
          *(us4*)(Ps + qrow * 72 + mt * 16 + quad * 4) = pw;
        }
      }

      // ---- O^T += V^T * P^T  (wave reads only its own P rows; no barrier needed) ----
      for (int ks = 0; ks < 2; ++ks) {
        bs8 va[8];
        for (int dmt = 0; dmt < 8; ++dmt) {
          int d = dmt * 16 + l16;
          int c = ks * 4 + quad;
          int slot = c ^ (d & 7);
          va[dmt] = *(const bs8*)(Vs + d * 64 + slot * 8);
        }
        for (int nt = 0; nt < 2; ++nt) {
          int qrow = wid * 32 + nt * 16 + l16;
          bs8 pb = *(const bs8*)(Ps + qrow * 72 + ks * 32 + quad * 8);
          for (int dmt = 0; dmt < 8; ++dmt)
            o[dmt][nt] = __builtin_amdgcn_mfma_f32_16x16x32_bf16(va[dmt], pb,
                                                                 o[dmt][nt], 0, 0, 0);
        }
      }
    }
    __syncthreads();
  }

  // ---- epilogue: normalize and write y (bf16, [b][t][h*128+d]) ----
  for (int nt = 0; nt < 2; ++nt) {
    float inv = 1.0f / l_i[nt];
    int q = qw + nt * 16 + l16;
    ushort* yrow = yb + ((size_t)(b * TT + q) * NH + h) * HD;
    for (int dmt = 0; dmt < 8; ++dmt) {
      us4 w = {f2b(o[dmt][nt][0] * inv), f2b(o[dmt][nt][1] * inv),
               f2b(o[dmt][nt][2] * inv), f2b(o[dmt][nt][3] * inv)};
      *(us4*)(yrow + dmt * 16 + quad * 4) = w;
    }
  }
}

// ---------------- launch ----------------
extern "C" void kernel_launch(void* const* d_in, const int* in_sizes, int n_in,
                              void* d_out, int out_size, void* d_ws, size_t ws_size,
                              hipStream_t stream) {
  const float* x = (const float*)d_in[0];
  // d_in[1] = attn_mask: ignored (exact causal mask computed analytically)
  const float* Wq = (const float*)d_in[2];
  const float* Wk = (const float*)d_in[3];
  const float* Wv = (const float*)d_in[4];
  const float* Wo = (const float*)d_in[5];
  const float* wlog = (const float*)d_in[6];
  // d_in[7] = weight_values: unused by the reference

  char* ws = (char*)d_ws;
  ushort* xb = (ushort*)ws;   ws += (size_t)4096 * 2048 * 2;
  ushort* Wqt = (ushort*)ws;  ws += (size_t)2048 * 2048 * 2;
  ushort* Wkt = (ushort*)ws;  ws += (size_t)512 * 2048 * 2;
  ushort* Wvt = (ushort*)ws;  ws += (size_t)512 * 2048 * 2;
  ushort* Wot = (ushort*)ws;  ws += (size_t)2048 * 2048 * 2;
  ushort* qbuf = (ushort*)ws; ws += (size_t)4096 * 2048 * 2;
  ushort* kbuf = (ushort*)ws; ws += (size_t)2 * KVH * 2048 * 128 * 2;
  ushort* vbuf = (ushort*)ws; ws += (size_t)2 * KVH * 2048 * 128 * 2;
  ushort* ybuf = (ushort*)ws; ws += (size_t)4096 * 2048 * 2;

  dim3 tb(32, 8);
  cast_f32_bf16<<<8192, 256, 0, stream>>>(x, xb);
  transpose_cast<<<dim3(DM / 32, DM / 32), tb, 0, stream>>>(Wq, Wqt, DM, DM);
  transpose_cast<<<dim3(512 / 32, DM / 32), tb, 0, stream>>>(Wk, Wkt, DM, 512);
  transpose_cast<<<dim3(512 / 32, DM / 32), tb, 0, stream>>>(Wv, Wvt, DM, 512);
  transpose_cast<<<dim3(DM / 32, DM / 32), tb, 0, stream>>>(Wo, Wot, DM, DM);

  gemm_bt<0><<<dim3(16, 32), 256, 0, stream>>>(xb, Wqt, qbuf, 4096, 2048, 2048);
  gemm_bt<1><<<dim3(4, 32), 256, 0, stream>>>(xb, Wkt, kbuf, 4096, 512, 2048);
  gemm_bt<2><<<dim3(4, 32), 256, 0, stream>>>(xb, Wvt, vbuf, 4096, 512, 2048);

  attn_kernel<<<512, 256, 0, stream>>>(qbuf, kbuf, vbuf, ybuf, wlog);

  gemm_bt<3><<<dim3(16, 32), 256, 0, stream>>>(ybuf, Wot, d_out, 4096, 2048, 2048);
}